// Round 1
// baseline (277.021 us; speedup 1.0000x reference)
//
#include <hip/hip_runtime.h>
#include <hip/hip_bf16.h>
#include <cstdint>

// Workspace layout (bytes):
//   [0,        8388608)  xb   : x as bf16 [4096][1024]   (aliased later as ao)
//   [8388608, 14680064)  wqkvT: w_qkv^T bf16 [3072][1024]
//   [14680064,16777216)  wprojT: w_proj^T bf16 [1024][1024]
//   [16777216,25165824)  qb   : q (rope'd, *SCALE*log2e) bf16 [16][4096][64]
//   [25165824,33554432)  kb   : k (rope'd) bf16 [16][4096][64]
//   [33554432,41943040)  vT   : v^T bf16 [16][64][4096]
//   ao (attention out bf16 [4096][1024]) aliases xb.

#define TOK 4096
#define DIM_ 1024
#define NHEAD 16
#define HDIM 64
#define N3 3072
#define SCALE_LOG2E 0.18033688011112042f  // (1/8) * log2(e)

typedef __bf16 bf16_t;
typedef bf16_t bf16x8 __attribute__((ext_vector_type(8)));
typedef float floatx4 __attribute__((ext_vector_type(4)));

__device__ __forceinline__ void async_ld16(const bf16_t* g, bf16_t* l) {
  __builtin_amdgcn_global_load_lds(
      (const __attribute__((address_space(1))) void*)(g),
      (__attribute__((address_space(3))) void*)(l), 16, 0, 0);
}

// ---------------- fused prep: cvt x -> bf16; transpose+cvt w_qkv, w_proj ----
// blocks [0,4096): xb; [4096,7168): wqkvT; [7168,8192): wprojT
__global__ __launch_bounds__(256) void k_prep(
    const float* __restrict__ x, const float* __restrict__ w_qkv,
    const float* __restrict__ w_proj, bf16_t* __restrict__ xb,
    bf16_t* __restrict__ wqkvT, bf16_t* __restrict__ wprojT) {
  __shared__ float tile[32][33];
  const int b = blockIdx.x;
  if (b < 4096) {
    int i = b * 256 + threadIdx.x;
    float4 v = ((const float4*)x)[i];
    union { bf16_t bb[4]; uint64_t u; } p;
    p.bb[0] = (bf16_t)v.x; p.bb[1] = (bf16_t)v.y;
    p.bb[2] = (bf16_t)v.z; p.bb[3] = (bf16_t)v.w;
    ((uint64_t*)xb)[i] = p.u;
    return;
  }
  const float* in; bf16_t* out; int R, C, c0, r0;
  if (b < 7168) {
    int bb = b - 4096; in = w_qkv; out = wqkvT; R = 1024; C = 3072;
    c0 = (bb % 96) * 32; r0 = (bb / 96) * 32;
  } else {
    int bb = b - 7168; in = w_proj; out = wprojT; R = 1024; C = 1024;
    c0 = (bb % 32) * 32; r0 = (bb / 32) * 32;
  }
  int tx = threadIdx.x & 31, ty = threadIdx.x >> 5;
#pragma unroll
  for (int i = 0; i < 4; i++) {
    int r = ty + i * 8;
    tile[r][tx] = in[(size_t)(r0 + r) * C + c0 + tx];
  }
  __syncthreads();
#pragma unroll
  for (int i = 0; i < 4; i++) {
    int c = ty + i * 8;
    out[(size_t)(c0 + c) * R + r0 + tx] = (bf16_t)tile[tx][c];
  }
}

// ---------------- QKV GEMM + bias + RoPE + scatter ----------------
__global__ __launch_bounds__(256) void k_qkv(
    const bf16_t* __restrict__ A,   // [4096][1024]
    const bf16_t* __restrict__ Bt,  // [3072][1024]
    const float* __restrict__ bias, // [3072]
    const float* __restrict__ cs,   // [4096][32]
    const float* __restrict__ sn,   // [4096][32]
    bf16_t* __restrict__ qb, bf16_t* __restrict__ kb, bf16_t* __restrict__ vT) {
  constexpr int K = 1024, BK = 32;
  __shared__ bf16_t As[128 * BK] __attribute__((aligned(16)));
  __shared__ bf16_t Bs[128 * BK] __attribute__((aligned(16)));
  const int t = threadIdx.x;
  const int lane = t & 63, w = t >> 6;
  const int lrow = lane & 15, quad = lane >> 4;
  const int m0 = blockIdx.y * 128, n0 = blockIdx.x * 128;
  const int wm = (w >> 1) * 64, wn = (w & 1) * 64;

  const floatx4 ZV = {0.f, 0.f, 0.f, 0.f};
  floatx4 acc[4][4];
#pragma unroll
  for (int i = 0; i < 4; i++)
#pragma unroll
    for (int j = 0; j < 4; j++) acc[i][j] = ZV;

  for (int kt = 0; kt < K; kt += BK) {
#pragma unroll
    for (int r = 0; r < 2; r++) {
      int idx = r * 256 + t;
      int lbase = (r * 256 + w * 64) * 8;
      async_ld16(&A[(size_t)(m0 + (idx >> 2)) * K + kt + (idx & 3) * 8], &As[lbase]);
      async_ld16(&Bt[(size_t)(n0 + (idx >> 2)) * K + kt + (idx & 3) * 8], &Bs[lbase]);
    }
    __syncthreads();
    bf16x8 af[4], bf[4];
#pragma unroll
    for (int i = 0; i < 4; i++)
      af[i] = *(const bf16x8*)&As[(wm + i * 16 + lrow) * BK + quad * 8];
#pragma unroll
    for (int i = 0; i < 4; i++)
      bf[i] = *(const bf16x8*)&Bs[(wn + i * 16 + lrow) * BK + quad * 8];
#pragma unroll
    for (int mi = 0; mi < 4; mi++)
#pragma unroll
      for (int ni = 0; ni < 4; ni++)
        acc[mi][ni] = __builtin_amdgcn_mfma_f32_16x16x32_bf16(af[mi], bf[ni], acc[mi][ni], 0, 0, 0);
    __syncthreads();
  }

  // Epilogue: wave covers cols [c0, c0+64) = exactly one head of one of q/k/v.
  const int c0 = n0 + wn;
  const int seg = c0 >> 10;           // 0=q 1=k 2=v
  const int h = (c0 & 1023) >> 6;
  float bv[4];
#pragma unroll
  for (int ni = 0; ni < 4; ni++) bv[ni] = bias[c0 + ni * 16 + lrow];

  if (seg < 2) {
    bf16_t* base = ((seg == 0) ? qb : kb) + (size_t)h * TOK * HDIM;
    const float qs = (seg == 0) ? SCALE_LOG2E : 1.0f;
#pragma unroll
    for (int mi = 0; mi < 4; mi++) {
#pragma unroll
      for (int reg = 0; reg < 4; reg++) {
        const int r = m0 + wm + mi * 16 + quad * 4 + reg;
        const float c_lo = cs[r * 32 + lrow];
        const float c_hi = cs[r * 32 + 16 + lrow];
        const float s_lo = sn[r * 32 + lrow];
        const float s_hi = sn[r * 32 + 16 + lrow];
        const float v0 = acc[mi][0][reg] + bv[0];
        const float v1 = acc[mi][1][reg] + bv[1];
        const float v2 = acc[mi][2][reg] + bv[2];
        const float v3 = acc[mi][3][reg] + bv[3];
        // RoPE: d<32: v*cos - v[d+32]*sin ; d>=32: v*cos + v[d-32]*sin
        const float o0 = (v0 * c_lo - v2 * s_lo) * qs;
        const float o1 = (v1 * c_hi - v3 * s_hi) * qs;
        const float o2 = (v2 * c_lo + v0 * s_lo) * qs;
        const float o3 = (v3 * c_hi + v1 * s_hi) * qs;
        bf16_t* rp = base + (size_t)r * HDIM + lrow;
        rp[0]  = (bf16_t)o0;
        rp[16] = (bf16_t)o1;
        rp[32] = (bf16_t)o2;
        rp[48] = (bf16_t)o3;
      }
    }
  } else {
    // V: store transposed [h][d][n]; 4 acc regs = 4 consecutive rows -> 8B store
    bf16_t* base = vT + (size_t)h * HDIM * TOK;
#pragma unroll
    for (int mi = 0; mi < 4; mi++) {
      const int rbase = m0 + wm + mi * 16 + quad * 4;
#pragma unroll
      for (int ni = 0; ni < 4; ni++) {
        union { bf16_t b[4]; uint64_t u; } p;
#pragma unroll
        for (int reg = 0; reg < 4; reg++) p.b[reg] = (bf16_t)(acc[mi][ni][reg] + bv[ni]);
        *(uint64_t*)&base[(size_t)(ni * 16 + lrow) * TOK + rbase] = p.u;
      }
    }
  }
}

// ---------------- flash attention v8: occupancy (16 waves/CU) ----------------
// Was: 512 blocks x 50KB LDS -> 2 blocks/CU = 2 waves/SIMD; MFMA 33% / VALU 36%
// / LDS ~34% all unsaturated -> latency-bound. Now: 64q blocks (wave = 32q x
// 32k, ni=2), grid = 1024 = 4 blocks/CU; V fragments read DIRECT from global
// (V per head 512KB; 2 heads/XCD via swizzle -> L2-resident) so LDS drops to
// Ks 16KB + Ps 9KB = 25.6KB -> 4 blocks/CU = 16 waves/CU. K stays LDS-staged
// (K direct-global would double L2 frag traffic past its ~34TB/s ceiling).
// Ps: per-wave [32 q][36] bf16 (stride-36: 18r mod 32 covers all 16 even
// banks -> uniform 4-way b64 = port minimum). Fixed-max softmax (proven
// v4-v6). Epilogue merges kh halves via Ks (dead after loop).
__global__ __launch_bounds__(256, 4) void k_attn(
    const bf16_t* __restrict__ qb, const bf16_t* __restrict__ kb,
    const bf16_t* __restrict__ vT, bf16_t* __restrict__ ao) {
  __shared__ bf16_t Ks[2][64 * 64] __attribute__((aligned(16)));
  __shared__ bf16_t Ps[4][32 * 36] __attribute__((aligned(16)));
  const int t = threadIdx.x, lane = t & 63, w = t >> 6;
  const int lrow = lane & 15, quad = lane >> 4;
  const int qg = w & 1, kh = w >> 1;
  // XCD swizzle: 8 XCDs round-robin on blockIdx.x%8 -> pin 2 heads per XCD so
  // that XCD's K+V working set (2MB) is L2-resident.
  const int bx = blockIdx.x;
  const int h = ((bx & 7) << 1) | ((bx >> 3) & 1);
  const int q0 = (bx >> 4) * 64;
  const bf16_t* qh = qb + (size_t)h * TOK * HDIM;
  const bf16_t* khp = kb + (size_t)h * TOK * HDIM;
  const bf16_t* vhp = vT + (size_t)h * HDIM * TOK;
  bf16_t* Pw = &Ps[w][0];

  // K staging (256 threads, 2 rounds; 64 rows x 8 chunks).
  // XOR swizzle folded into the GLOBAL side; LDS side lane-linear.
  const int ksrc = (t >> 3) * HDIM + (((t & 7) ^ ((t >> 3) & 7)) * 8);

  // Q B-fragments (B[n=q][k=d]) straight from global, once.
  bf16x8 qf[2][2];
#pragma unroll
  for (int ni = 0; ni < 2; ni++)
#pragma unroll
    for (int ks = 0; ks < 2; ks++)
      qf[ni][ks] = *(const bf16x8*)&qh[(size_t)(q0 + qg * 32 + ni * 16 + lrow) * HDIM + ks * 32 + quad * 8];

  const floatx4 ZV = {0.f, 0.f, 0.f, 0.f};
  floatx4 o[4][2];            // O^T [d-tile][ni] over this wave's key-half
  floatx4 lacc[2] = {ZV, ZV};
#pragma unroll
  for (int d = 0; d < 4; d++)
#pragma unroll
    for (int ni = 0; ni < 2; ni++) o[d][ni] = ZV;

  // Prologue: stage K tile 0 into buffer 0.
#pragma unroll
  for (int r = 0; r < 2; r++)
    async_ld16(&khp[(size_t)(r * 32) * HDIM + ksrc], &Ks[0][r * 2048 + t * 8]);

  for (int it = 0; it < TOK / 64; ++it) {
    const int b = it & 1;
    __syncthreads();   // buffer b staged (prefetched a full phase ago)
    if (it + 1 < TOK / 64) {
      const size_t j1 = (size_t)(it + 1) * 64;
#pragma unroll
      for (int r = 0; r < 2; r++)
        async_ld16(&khp[(j1 + r * 32) * HDIM + ksrc], &Ks[b ^ 1][r * 2048 + t * 8]);
    }

    // ---- V fragments direct from global, issued early: ~200cy L2 latency
    // hides under QK^T + softmax (~1000+cy).
    bf16x8 vf[4];
#pragma unroll
    for (int dt = 0; dt < 4; dt++)
      vf[dt] = *(const bf16x8*)&vhp[(size_t)(dt * 16 + lrow) * TOK + it * 64 + kh * 32 + quad * 8];

    // ---- S^T quadrant: keys kh*32+mi*16+quad*4+reg, q = qg*32+ni*16+lrow
    floatx4 s[2][2];
#pragma unroll
    for (int mi = 0; mi < 2; mi++)
#pragma unroll
      for (int ni = 0; ni < 2; ni++) s[mi][ni] = ZV;
#pragma unroll
    for (int ks = 0; ks < 2; ks++)
#pragma unroll
      for (int mi = 0; mi < 2; mi++) {
        bf16x8 kf = *(const bf16x8*)&Ks[b][(kh * 32 + mi * 16 + lrow) * 64 + (((ks * 4 + quad) ^ (lrow & 7)) * 8)];
#pragma unroll
        for (int ni = 0; ni < 2; ni++)
          s[mi][ni] = __builtin_amdgcn_mfma_f32_16x16x32_bf16(kf, qf[ni][ks], s[mi][ni], 0, 0, 0);
      }

    // ---- P = exp2(S) (fixed-max), vector l-partials
#pragma unroll
    for (int mi = 0; mi < 2; mi++)
#pragma unroll
      for (int ni = 0; ni < 2; ni++) {
#pragma unroll
        for (int reg = 0; reg < 4; reg++)
          s[mi][ni][reg] = __builtin_amdgcn_exp2f(s[mi][ni][reg]);
        lacc[ni] += s[mi][ni];
      }

    // ---- P -> Ps (wave-private, stride 36, b64 chunk = mi*4+quad)
#pragma unroll
    for (int mi = 0; mi < 2; mi++)
#pragma unroll
      for (int ni = 0; ni < 2; ni++) {
        union { bf16_t b4[4]; uint64_t u; } p;
#pragma unroll
        for (int reg = 0; reg < 4; reg++) p.b4[reg] = (bf16_t)s[mi][ni][reg];
        *(uint64_t*)&Pw[(ni * 16 + lrow) * 36 + (mi * 4 + quad) * 4] = p.u;
      }

    // ---- O^T += V^T * P over this wave's 32-key half (K=32, 1 step)
    bf16x8 pf[2];
#pragma unroll
    for (int ni = 0; ni < 2; ni++) {
      const int row = (ni * 16 + lrow) * 36;
      union { uint64_t u[2]; bf16x8 v; } pp;
      pp.u[0] = *(const uint64_t*)&Pw[row + quad * 8];
      pp.u[1] = *(const uint64_t*)&Pw[row + quad * 8 + 4];
      pf[ni] = pp.v;
    }
#pragma unroll
    for (int dt = 0; dt < 4; dt++)
#pragma unroll
      for (int ni = 0; ni < 2; ni++)
        o[dt][ni] = __builtin_amdgcn_mfma_f32_16x16x32_bf16(vf[dt], pf[ni], o[dt][ni], 0, 0, 0);
  }

  // ---- epilogue: merge kh halves. qg selects an 8KB half of Ks (dead now).
  __syncthreads();
  float* Mrg = (float*)&Ks[qg][0];   // 32q x 64d fp32 (8KB)
  float* Lmrg = (float*)&Ps[0][0];   // 64 floats
  float lq[2];
#pragma unroll
  for (int ni = 0; ni < 2; ni++) {
    float l = lacc[ni][0] + lacc[ni][1] + lacc[ni][2] + lacc[ni][3];
    l += __shfl_xor(l, 16, 64);
    l += __shfl_xor(l, 32, 64);
    lq[ni] = l;
  }
  if (kh == 1) {
#pragma unroll
    for (int ni = 0; ni < 2; ni++) {
#pragma unroll
      for (int dt = 0; dt < 4; dt++)
        *(floatx4*)&Mrg[(ni * 16 + lrow) * 64 + dt * 16 + quad * 4] = o[dt][ni];
      if (quad == 0) Lmrg[qg * 32 + ni * 16 + lrow] = lq[ni];
    }
  }
  __syncthreads();
  if (kh == 0) {
#pragma unroll
    for (int ni = 0; ni < 2; ni++) {
      const float l = lq[ni] + Lmrg[qg * 32 + ni * 16 + lrow];
      const float inv = 1.0f / l;
      const int qrow = q0 + qg * 32 + ni * 16 + lrow;
#pragma unroll
      for (int dt = 0; dt < 4; dt++) {
        floatx4 ov = *(const floatx4*)&Mrg[(ni * 16 + lrow) * 64 + dt * 16 + quad * 4];
        union { bf16_t b4[4]; uint64_t u; } p;
#pragma unroll
        for (int reg = 0; reg < 4; reg++) p.b4[reg] = (bf16_t)((o[dt][ni][reg] + ov[reg]) * inv);
        *(uint64_t*)&ao[(size_t)qrow * DIM_ + h * HDIM + dt * 16 + quad * 4] = p.u;
      }
    }
  }
}

// ---------------- proj GEMM + bias (fp32 out), 64x128 tiles ----------------
__global__ __launch_bounds__(256) void k_proj(
    const bf16_t* __restrict__ A,   // [4096][1024]
    const bf16_t* __restrict__ Bt,  // [1024][1024]
    const float* __restrict__ bias, float* __restrict__ out) {
  constexpr int K = 1024, BK = 32;
  __shared__ bf16_t As[64 * BK] __attribute__((aligned(16)));
  __shared__ bf16_t Bs[128 * BK] __attribute__((aligned(16)));
  const int t = threadIdx.x;
  const int lane = t & 63, w = t >> 6;
  const int lrow = lane & 15, quad = lane >> 4;
  const int m0 = blockIdx.y * 64, n0 = blockIdx.x * 128;
  const int wm = (w >> 1) * 32, wn = (w & 1) * 64;

  const floatx4 ZV = {0.f, 0.f, 0.f, 0.f};
  floatx4 acc[2][4];
#pragma unroll
  for (int i = 0; i < 2; i++)
#pragma unroll
    for (int j = 0; j < 4; j++) acc[i][j] = ZV;

  for (int kt = 0; kt < K; kt += BK) {
    async_ld16(&A[(size_t)(m0 + (t >> 2)) * K + kt + (t & 3) * 8], &As[w * 512]);
#pragma unroll
    for (int r = 0; r < 2; r++) {
      int idx = r * 256 + t;
      async_ld16(&Bt[(size_t)(n0 + (idx >> 2)) * K + kt + (idx & 3) * 8],
                 &Bs[(r * 256 + w * 64) * 8]);
    }
    __syncthreads();
    bf16x8 af[2], bf[4];
#pragma unroll
    for (int i = 0; i < 2; i++)
      af[i] = *(const bf16x8*)&As[(wm + i * 16 + lrow) * BK + quad * 8];
#pragma unroll
    for (int i = 0; i < 4; i++)
      bf[i] = *(const bf16x8*)&Bs[(wn + i * 16 + lrow) * BK + quad * 8];
#pragma unroll
    for (int mi = 0; mi < 2; mi++)
#pragma unroll
      for (int ni = 0; ni < 4; ni++)
        acc[mi][ni] = __builtin_amdgcn_mfma_f32_16x16x32_bf16(af[mi], bf[ni], acc[mi][ni], 0, 0, 0);
    __syncthreads();
  }

  const int c0 = n0 + wn;
#pragma unroll
  for (int ni = 0; ni < 4; ni++) {
    float bv = bias[c0 + ni * 16 + lrow];
#pragma unroll
    for (int mi = 0; mi < 2; mi++)
#pragma unroll
      for (int reg = 0; reg < 4; reg++) {
        int r = m0 + wm + mi * 16 + quad * 4 + reg;
        out[(size_t)r * DIM_ + c0 + ni * 16 + lrow] = acc[mi][ni][reg] + bv;
      }
  }
}

extern "C" void kernel_launch(void* const* d_in, const int* in_sizes, int n_in,
                              void* d_out, int out_size, void* d_ws, size_t ws_size,
                              hipStream_t stream) {
  const float* x      = (const float*)d_in[0];
  const float* cs     = (const float*)d_in[1];
  const float* sn     = (const float*)d_in[2];
  const float* w_qkv  = (const float*)d_in[3];
  const float* b_qkv  = (const float*)d_in[4];
  const float* w_proj = (const float*)d_in[5];
  const float* b_proj = (const float*)d_in[6];
  float* out = (float*)d_out;

  char* ws = (char*)d_ws;
  bf16_t* xb     = (bf16_t*)(ws);
  bf16_t* wqkvT  = (bf16_t*)(ws + 8388608);
  bf16_t* wprojT = (bf16_t*)(ws + 14680064);
  bf16_t* qb     = (bf16_t*)(ws + 16777216);
  bf16_t* kb     = (bf16_t*)(ws + 25165824);
  bf16_t* vT     = (bf16_t*)(ws + 33554432);
  bf16_t* ao     = xb;  // x is dead after k_qkv; reuse its region

  k_prep<<<dim3(8192), dim3(256), 0, stream>>>(x, w_qkv, w_proj, xb, wqkvT, wprojT);
  k_qkv<<<dim3(24, 32), dim3(256), 0, stream>>>(xb, wqkvT, b_qkv, cs, sn, qb, kb, vT);
  k_attn<<<dim3(1024), dim3(256), 0, stream>>>(qb, kb, vT, ao);
  k_proj<<<dim3(8, 64), dim3(256), 0, stream>>>(ao, wprojT, b_proj, out);
}

// Round 2
// 240.437 us; speedup vs baseline: 1.1522x; 1.1522x over previous
//
#include <hip/hip_runtime.h>
#include <hip/hip_bf16.h>
#include <cstdint>

// Workspace layout (bytes):
//   [0,        8388608)  xb   : x as bf16 [4096][1024]   (aliased later as ao)
//   [8388608, 14680064)  wqkvT: w_qkv^T bf16 [3072][1024]
//   [14680064,16777216)  wprojT: w_proj^T bf16 [1024][1024]
//   [16777216,25165824)  qb   : q (rope'd, *SCALE*log2e) bf16 [16][4096][64]
//   [25165824,33554432)  kb   : k (rope'd) bf16 [16][4096][64]
//   [33554432,41943040)  vT   : v^T bf16 [16][64][4096]
//   ao (attention out bf16 [4096][1024]) aliases xb.

#define TOK 4096
#define DIM_ 1024
#define NHEAD 16
#define HDIM 64
#define N3 3072
#define SCALE_LOG2E 0.18033688011112042f  // (1/8) * log2(e)

typedef __bf16 bf16_t;
typedef bf16_t bf16x8 __attribute__((ext_vector_type(8)));
typedef float floatx4 __attribute__((ext_vector_type(4)));

__device__ __forceinline__ void async_ld16(const bf16_t* g, bf16_t* l) {
  __builtin_amdgcn_global_load_lds(
      (const __attribute__((address_space(1))) void*)(g),
      (__attribute__((address_space(3))) void*)(l), 16, 0, 0);
}

__device__ __forceinline__ uint32_t pk2(float lo, float hi) {
  union { bf16_t b[2]; uint32_t u; } p;
  p.b[0] = (bf16_t)lo; p.b[1] = (bf16_t)hi;
  return p.u;  // compiler fuses to v_cvt_pk_bf16_f32
}

// ---------------- fused prep: cvt x -> bf16; transpose+cvt w_qkv, w_proj ----
// blocks [0,4096): xb; [4096,7168): wqkvT; [7168,8192): wprojT
__global__ __launch_bounds__(256) void k_prep(
    const float* __restrict__ x, const float* __restrict__ w_qkv,
    const float* __restrict__ w_proj, bf16_t* __restrict__ xb,
    bf16_t* __restrict__ wqkvT, bf16_t* __restrict__ wprojT) {
  __shared__ float tile[32][33];
  const int b = blockIdx.x;
  if (b < 4096) {
    int i = b * 256 + threadIdx.x;
    float4 v = ((const float4*)x)[i];
    union { bf16_t bb[4]; uint64_t u; } p;
    p.bb[0] = (bf16_t)v.x; p.bb[1] = (bf16_t)v.y;
    p.bb[2] = (bf16_t)v.z; p.bb[3] = (bf16_t)v.w;
    ((uint64_t*)xb)[i] = p.u;
    return;
  }
  const float* in; bf16_t* out; int R, C, c0, r0;
  if (b < 7168) {
    int bb = b - 4096; in = w_qkv; out = wqkvT; R = 1024; C = 3072;
    c0 = (bb % 96) * 32; r0 = (bb / 96) * 32;
  } else {
    int bb = b - 7168; in = w_proj; out = wprojT; R = 1024; C = 1024;
    c0 = (bb % 32) * 32; r0 = (bb / 32) * 32;
  }
  int tx = threadIdx.x & 31, ty = threadIdx.x >> 5;
#pragma unroll
  for (int i = 0; i < 4; i++) {
    int r = ty + i * 8;
    tile[r][tx] = in[(size_t)(r0 + r) * C + c0 + tx];
  }
  __syncthreads();
#pragma unroll
  for (int i = 0; i < 4; i++) {
    int c = ty + i * 8;
    out[(size_t)(c0 + c) * R + r0 + tx] = (bf16_t)tile[tx][c];
  }
}

// ---------------- QKV GEMM + bias + RoPE + scatter ----------------
__global__ __launch_bounds__(256) void k_qkv(
    const bf16_t* __restrict__ A,   // [4096][1024]
    const bf16_t* __restrict__ Bt,  // [3072][1024]
    const float* __restrict__ bias, // [3072]
    const float* __restrict__ cs,   // [4096][32]
    const float* __restrict__ sn,   // [4096][32]
    bf16_t* __restrict__ qb, bf16_t* __restrict__ kb, bf16_t* __restrict__ vT) {
  constexpr int K = 1024, BK = 32;
  __shared__ bf16_t As[128 * BK] __attribute__((aligned(16)));
  __shared__ bf16_t Bs[128 * BK] __attribute__((aligned(16)));
  const int t = threadIdx.x;
  const int lane = t & 63, w = t >> 6;
  const int lrow = lane & 15, quad = lane >> 4;
  const int m0 = blockIdx.y * 128, n0 = blockIdx.x * 128;
  const int wm = (w >> 1) * 64, wn = (w & 1) * 64;

  const floatx4 ZV = {0.f, 0.f, 0.f, 0.f};
  floatx4 acc[4][4];
#pragma unroll
  for (int i = 0; i < 4; i++)
#pragma unroll
    for (int j = 0; j < 4; j++) acc[i][j] = ZV;

  for (int kt = 0; kt < K; kt += BK) {
#pragma unroll
    for (int r = 0; r < 2; r++) {
      int idx = r * 256 + t;
      int lbase = (r * 256 + w * 64) * 8;
      async_ld16(&A[(size_t)(m0 + (idx >> 2)) * K + kt + (idx & 3) * 8], &As[lbase]);
      async_ld16(&Bt[(size_t)(n0 + (idx >> 2)) * K + kt + (idx & 3) * 8], &Bs[lbase]);
    }
    __syncthreads();
    bf16x8 af[4], bf[4];
#pragma unroll
    for (int i = 0; i < 4; i++)
      af[i] = *(const bf16x8*)&As[(wm + i * 16 + lrow) * BK + quad * 8];
#pragma unroll
    for (int i = 0; i < 4; i++)
      bf[i] = *(const bf16x8*)&Bs[(wn + i * 16 + lrow) * BK + quad * 8];
#pragma unroll
    for (int mi = 0; mi < 4; mi++)
#pragma unroll
      for (int ni = 0; ni < 4; ni++)
        acc[mi][ni] = __builtin_amdgcn_mfma_f32_16x16x32_bf16(af[mi], bf[ni], acc[mi][ni], 0, 0, 0);
    __syncthreads();
  }

  // Epilogue: wave covers cols [c0, c0+64) = exactly one head of one of q/k/v.
  const int c0 = n0 + wn;
  const int seg = c0 >> 10;           // 0=q 1=k 2=v
  const int h = (c0 & 1023) >> 6;
  float bv[4];
#pragma unroll
  for (int ni = 0; ni < 4; ni++) bv[ni] = bias[c0 + ni * 16 + lrow];

  if (seg < 2) {
    bf16_t* base = ((seg == 0) ? qb : kb) + (size_t)h * TOK * HDIM;
    const float qs = (seg == 0) ? SCALE_LOG2E : 1.0f;
#pragma unroll
    for (int mi = 0; mi < 4; mi++) {
#pragma unroll
      for (int reg = 0; reg < 4; reg++) {
        const int r = m0 + wm + mi * 16 + quad * 4 + reg;
        const float c_lo = cs[r * 32 + lrow];
        const float c_hi = cs[r * 32 + 16 + lrow];
        const float s_lo = sn[r * 32 + lrow];
        const float s_hi = sn[r * 32 + 16 + lrow];
        const float v0 = acc[mi][0][reg] + bv[0];
        const float v1 = acc[mi][1][reg] + bv[1];
        const float v2 = acc[mi][2][reg] + bv[2];
        const float v3 = acc[mi][3][reg] + bv[3];
        // RoPE: d<32: v*cos - v[d+32]*sin ; d>=32: v*cos + v[d-32]*sin
        const float o0 = (v0 * c_lo - v2 * s_lo) * qs;
        const float o1 = (v1 * c_hi - v3 * s_hi) * qs;
        const float o2 = (v2 * c_lo + v0 * s_lo) * qs;
        const float o3 = (v3 * c_hi + v1 * s_hi) * qs;
        bf16_t* rp = base + (size_t)r * HDIM + lrow;
        rp[0]  = (bf16_t)o0;
        rp[16] = (bf16_t)o1;
        rp[32] = (bf16_t)o2;
        rp[48] = (bf16_t)o3;
      }
    }
  } else {
    // V: store transposed [h][d][n]; 4 acc regs = 4 consecutive rows -> 8B store
    bf16_t* base = vT + (size_t)h * HDIM * TOK;
#pragma unroll
    for (int mi = 0; mi < 4; mi++) {
      const int rbase = m0 + wm + mi * 16 + quad * 4;
#pragma unroll
      for (int ni = 0; ni < 4; ni++) {
        union { bf16_t b[4]; uint64_t u; } p;
#pragma unroll
        for (int reg = 0; reg < 4; reg++) p.b[reg] = (bf16_t)(acc[mi][ni][reg] + bv[ni]);
        *(uint64_t*)&base[(size_t)(ni * 16 + lrow) * TOK + rbase] = p.u;
      }
    }
  }
}

// ---------------- flash attention v9: v7 + in-register P exchange ----------
// v7 structure (proven 99us): 4-wave blocks, wave = 64q x 32k, K+V LDS
// double-buffered, fixed-max softmax. v8 (64q blocks + direct-global V)
// regressed: waiting on V frags drained the K-prefetch vmcnt every iter.
// v9 reverts to v7 and removes the LDS P round-trip instead: the S^T
// fragment -> PV B-fragment remap is a block transpose over
// (lane-bit5, lane-bit4) x (register index), done in-register with
// permlane32_swap + permlane16_swap (T12 pattern on the quad axis).
// Removes 16 of 24 DS ops/wave-iter (~1GB total LDS traffic) and the two
// chained ~120cy LDS latencies between QK^T and PV. Ps LDS freed.
__global__ __launch_bounds__(256, 2) void k_attn(
    const bf16_t* __restrict__ qb, const bf16_t* __restrict__ kb,
    const bf16_t* __restrict__ vT, bf16_t* __restrict__ ao) {
  __shared__ bf16_t Ks[2][64 * 64] __attribute__((aligned(16)));
  __shared__ bf16_t Vs[2][64 * 64] __attribute__((aligned(16)));
  __shared__ float Lmrg[128];
  const int t = threadIdx.x, lane = t & 63, w = t >> 6;
  const int lrow = lane & 15, quad = lane >> 4;
  const int qg = w & 1, kh = w >> 1;
  const int h = blockIdx.x & 15;
  const int q0 = (blockIdx.x >> 4) * 128;
  const bf16_t* qh = qb + (size_t)h * TOK * HDIM;
  const bf16_t* khp = kb + (size_t)h * TOK * HDIM;
  const bf16_t* vhp = vT + (size_t)h * HDIM * TOK;

  // Staging (256 threads, 2 rounds each for K and V; 64 rows x 8 chunks).
  // XOR swizzle folded into the GLOBAL side; LDS side lane-linear.
  const int ksrc = (t >> 3) * HDIM + (((t & 7) ^ ((t >> 3) & 7)) * 8);
  const int vsrc = (t >> 3) * TOK + (((t & 7) ^ ((t >> 3) & 7)) * 8);

  // Q B-fragments (B[n=q][k=d]) straight from global, once.
  bf16x8 qf[4][2];
#pragma unroll
  for (int ni = 0; ni < 4; ni++)
#pragma unroll
    for (int ks = 0; ks < 2; ks++)
      qf[ni][ks] = *(const bf16x8*)&qh[(size_t)(q0 + qg * 64 + ni * 16 + lrow) * HDIM + ks * 32 + quad * 8];

  const floatx4 ZV = {0.f, 0.f, 0.f, 0.f};
  floatx4 o[4][4];            // O^T [d-tile][ni] over this wave's key-half
  floatx4 lacc[4] = {ZV, ZV, ZV, ZV};
#pragma unroll
  for (int d = 0; d < 4; d++)
#pragma unroll
    for (int ni = 0; ni < 4; ni++) o[d][ni] = ZV;

  // Prologue: stage tile 0 into buffer 0.
#pragma unroll
  for (int r = 0; r < 2; r++) {
    async_ld16(&khp[(size_t)(r * 32) * HDIM + ksrc], &Ks[0][r * 2048 + t * 8]);
    async_ld16(&vhp[(size_t)(r * 32) * TOK + vsrc], &Vs[0][r * 2048 + t * 8]);
  }

  for (int it = 0; it < TOK / 64; ++it) {
    const int b = it & 1;
    __syncthreads();   // buffer b staged (prefetched a full phase ago)
    if (it + 1 < TOK / 64) {
      const int j1 = (it + 1) * 64;
#pragma unroll
      for (int r = 0; r < 2; r++) {
        async_ld16(&khp[((size_t)j1 + r * 32) * HDIM + ksrc], &Ks[b ^ 1][r * 2048 + t * 8]);
        async_ld16(&vhp[(size_t)(r * 32) * TOK + j1 + vsrc], &Vs[b ^ 1][r * 2048 + t * 8]);
      }
    }

    // ---- S^T quadrant: keys kh*32+mi*16+quad*4+reg, q = qg*64+ni*16+lrow
    floatx4 s[2][4];
#pragma unroll
    for (int mi = 0; mi < 2; mi++)
#pragma unroll
      for (int ni = 0; ni < 4; ni++) s[mi][ni] = ZV;
#pragma unroll
    for (int ks = 0; ks < 2; ks++)
#pragma unroll
      for (int mi = 0; mi < 2; mi++) {
        bf16x8 kf = *(const bf16x8*)&Ks[b][(kh * 32 + mi * 16 + lrow) * 64 + (((ks * 4 + quad) ^ (lrow & 7)) * 8)];
#pragma unroll
        for (int ni = 0; ni < 4; ni++)
          s[mi][ni] = __builtin_amdgcn_mfma_f32_16x16x32_bf16(kf, qf[ni][ks], s[mi][ni], 0, 0, 0);
      }

    // ---- P = exp2(S) (fixed-max), vector l-partials
#pragma unroll
    for (int mi = 0; mi < 2; mi++)
#pragma unroll
      for (int ni = 0; ni < 4; ni++) {
#pragma unroll
        for (int reg = 0; reg < 4; reg++)
          s[mi][ni][reg] = __builtin_amdgcn_exp2f(s[mi][ni][reg]);
        lacc[ni] += s[mi][ni];
      }

    // ---- S^T frag -> PV B-frag, fully in-register.
    // Source: lane (lrow, quad) holds key (mi*16 + quad*4 + reg), q-row
    // (ni*16+lrow). Target pf[ni]: lane (lrow, q) needs keys 8q..8q+7.
    // With packs A0=pk(mi0 r0,r1) A1=pk(mi0 r2,r3) B0/B1 same for mi1:
    //   stage1 (permlane32_swap): exchange lane-bit5 <-> pack bit (A/B)
    //   stage2 (permlane16_swap): exchange lane-bit4 <-> stage1 reg index
    // Result regs R[c][d]: pf dwords = [R00, R01, R10, R11]. All moves stay
    // within the same lrow, matching the proven v7 Ps layout exactly.
    bf16x8 pf[4];
#pragma unroll
    for (int ni = 0; ni < 4; ni++) {
      uint32_t A0 = pk2(s[0][ni][0], s[0][ni][1]);
      uint32_t A1 = pk2(s[0][ni][2], s[0][ni][3]);
      uint32_t B0 = pk2(s[1][ni][0], s[1][ni][1]);
      uint32_t B1 = pk2(s[1][ni][2], s[1][ni][3]);
      auto u0 = __builtin_amdgcn_permlane32_swap(A0, B0, false, false);  // {U00,U10}
      auto u1 = __builtin_amdgcn_permlane32_swap(A1, B1, false, false);  // {U01,U11}
      auto c0 = __builtin_amdgcn_permlane16_swap(u0[0], u0[1], false, false);  // {R00,R10}
      auto c1 = __builtin_amdgcn_permlane16_swap(u1[0], u1[1], false, false);  // {R01,R11}
      union { uint32_t d[4]; bf16x8 v; } pp;
      pp.d[0] = c0[0]; pp.d[1] = c1[0]; pp.d[2] = c0[1]; pp.d[3] = c1[1];
      pf[ni] = pp.v;
    }

    // ---- O^T += V^T * P over this wave's 32-key half (K=32, 1 step)
#pragma unroll
    for (int dt = 0; dt < 4; dt++) {
      bf16x8 vf = *(const bf16x8*)&Vs[b][(dt * 16 + lrow) * 64 + (((kh * 4 + quad) ^ (lrow & 7)) * 8)];
#pragma unroll
      for (int ni = 0; ni < 4; ni++)
        o[dt][ni] = __builtin_amdgcn_mfma_f32_16x16x32_bf16(vf, pf[ni], o[dt][ni], 0, 0, 0);
    }
  }

  // ---- epilogue: merge kh halves. qg=0 -> Ks region, qg=1 -> Vs region.
  __syncthreads();
  float* Mrg = (qg == 0) ? (float*)&Ks[0][0] : (float*)&Vs[0][0];  // 64q x 64d fp32
  float lq[4];
#pragma unroll
  for (int ni = 0; ni < 4; ni++) {
    float l = lacc[ni][0] + lacc[ni][1] + lacc[ni][2] + lacc[ni][3];
    l += __shfl_xor(l, 16, 64);
    l += __shfl_xor(l, 32, 64);
    lq[ni] = l;
  }
  if (kh == 1) {
#pragma unroll
    for (int ni = 0; ni < 4; ni++) {
#pragma unroll
      for (int dt = 0; dt < 4; dt++)
        *(floatx4*)&Mrg[(ni * 16 + lrow) * 64 + dt * 16 + quad * 4] = o[dt][ni];
      if (quad == 0) Lmrg[qg * 64 + ni * 16 + lrow] = lq[ni];
    }
  }
  __syncthreads();
  if (kh == 0) {
#pragma unroll
    for (int ni = 0; ni < 4; ni++) {
      const float l = lq[ni] + Lmrg[qg * 64 + ni * 16 + lrow];
      const float inv = 1.0f / l;
      const int qrow = q0 + qg * 64 + ni * 16 + lrow;
#pragma unroll
      for (int dt = 0; dt < 4; dt++) {
        floatx4 ov = *(const floatx4*)&Mrg[(ni * 16 + lrow) * 64 + dt * 16 + quad * 4];
        union { bf16_t b4[4]; uint64_t u; } p;
#pragma unroll
        for (int reg = 0; reg < 4; reg++) p.b4[reg] = (bf16_t)((o[dt][ni][reg] + ov[reg]) * inv);
        *(uint64_t*)&ao[(size_t)qrow * DIM_ + h * HDIM + dt * 16 + quad * 4] = p.u;
      }
    }
  }
}

// ---------------- proj GEMM + bias (fp32 out), 64x128 tiles ----------------
__global__ __launch_bounds__(256) void k_proj(
    const bf16_t* __restrict__ A,   // [4096][1024]
    const bf16_t* __restrict__ Bt,  // [1024][1024]
    const float* __restrict__ bias, float* __restrict__ out) {
  constexpr int K = 1024, BK = 32;
  __shared__ bf16_t As[64 * BK] __attribute__((aligned(16)));
  __shared__ bf16_t Bs[128 * BK] __attribute__((aligned(16)));
  const int t = threadIdx.x;
  const int lane = t & 63, w = t >> 6;
  const int lrow = lane & 15, quad = lane >> 4;
  const int m0 = blockIdx.y * 64, n0 = blockIdx.x * 128;
  const int wm = (w >> 1) * 32, wn = (w & 1) * 64;

  const floatx4 ZV = {0.f, 0.f, 0.f, 0.f};
  floatx4 acc[2][4];
#pragma unroll
  for (int i = 0; i < 2; i++)
#pragma unroll
    for (int j = 0; j < 4; j++) acc[i][j] = ZV;

  for (int kt = 0; kt < K; kt += BK) {
    async_ld16(&A[(size_t)(m0 + (t >> 2)) * K + kt + (t & 3) * 8], &As[w * 512]);
#pragma unroll
    for (int r = 0; r < 2; r++) {
      int idx = r * 256 + t;
      async_ld16(&Bt[(size_t)(n0 + (idx >> 2)) * K + kt + (idx & 3) * 8],
                 &Bs[(r * 256 + w * 64) * 8]);
    }
    __syncthreads();
    bf16x8 af[2], bf[4];
#pragma unroll
    for (int i = 0; i < 2; i++)
      af[i] = *(const bf16x8*)&As[(wm + i * 16 + lrow) * BK + quad * 8];
#pragma unroll
    for (int i = 0; i < 4; i++)
      bf[i] = *(const bf16x8*)&Bs[(wn + i * 16 + lrow) * BK + quad * 8];
#pragma unroll
    for (int mi = 0; mi < 2; mi++)
#pragma unroll
      for (int ni = 0; ni < 4; ni++)
        acc[mi][ni] = __builtin_amdgcn_mfma_f32_16x16x32_bf16(af[mi], bf[ni], acc[mi][ni], 0, 0, 0);
    __syncthreads();
  }

  const int c0 = n0 + wn;
#pragma unroll
  for (int ni = 0; ni < 4; ni++) {
    float bv = bias[c0 + ni * 16 + lrow];
#pragma unroll
    for (int mi = 0; mi < 2; mi++)
#pragma unroll
      for (int reg = 0; reg < 4; reg++) {
        int r = m0 + wm + mi * 16 + quad * 4 + reg;
        out[(size_t)r * DIM_ + c0 + ni * 16 + lrow] = acc[mi][ni][reg] + bv;
      }
  }
}

extern "C" void kernel_launch(void* const* d_in, const int* in_sizes, int n_in,
                              void* d_out, int out_size, void* d_ws, size_t ws_size,
                              hipStream_t stream) {
  const float* x      = (const float*)d_in[0];
  const float* cs     = (const float*)d_in[1];
  const float* sn     = (const float*)d_in[2];
  const float* w_qkv  = (const float*)d_in[3];
  const float* b_qkv  = (const float*)d_in[4];
  const float* w_proj = (const float*)d_in[5];
  const float* b_proj = (const float*)d_in[6];
  float* out = (float*)d_out;

  char* ws = (char*)d_ws;
  bf16_t* xb     = (bf16_t*)(ws);
  bf16_t* wqkvT  = (bf16_t*)(ws + 8388608);
  bf16_t* wprojT = (bf16_t*)(ws + 14680064);
  bf16_t* qb     = (bf16_t*)(ws + 16777216);
  bf16_t* kb     = (bf16_t*)(ws + 25165824);
  bf16_t* vT     = (bf16_t*)(ws + 33554432);
  bf16_t* ao     = xb;  // x is dead after k_qkv; reuse its region

  k_prep<<<dim3(8192), dim3(256), 0, stream>>>(x, w_qkv, w_proj, xb, wqkvT, wprojT);
  k_qkv<<<dim3(24, 32), dim3(256), 0, stream>>>(xb, wqkvT, b_qkv, cs, sn, qb, kb, vT);
  k_attn<<<dim3(512), dim3(256), 0, stream>>>(qb, kb, vT, ao);
  k_proj<<<dim3(8, 64), dim3(256), 0, stream>>>(ao, wprojT, b_proj, out);
}

// Round 3
// 226.939 us; speedup vs baseline: 1.2207x; 1.0595x over previous
//
#include <hip/hip_runtime.h>
#include <hip/hip_bf16.h>
#include <cstdint>

// Workspace layout (bytes):
//   [0,        8388608)  xb   : x as bf16 [4096][1024]   (aliased later as ao)
//   [8388608, 14680064)  wqkvT: w_qkv^T bf16 [3072][1024]
//   [14680064,16777216)  wprojT: w_proj^T bf16 [1024][1024]
//   [16777216,25165824)  qb   : q (rope'd, *SCALE*log2e) bf16 [16][4096][64]
//   [25165824,33554432)  kb   : k (rope'd) bf16 [16][4096][64]
//   [33554432,41943040)  vT   : v^T bf16 [16][64][4096]
//   ao (attention out bf16 [4096][1024]) aliases xb.

#define TOK 4096
#define DIM_ 1024
#define NHEAD 16
#define HDIM 64
#define N3 3072
#define SCALE_LOG2E 0.18033688011112042f  // (1/8) * log2(e)

typedef __bf16 bf16_t;
typedef bf16_t bf16x8 __attribute__((ext_vector_type(8)));
typedef float floatx4 __attribute__((ext_vector_type(4)));

__device__ __forceinline__ void async_ld16(const bf16_t* g, bf16_t* l) {
  __builtin_amdgcn_global_load_lds(
      (const __attribute__((address_space(1))) void*)(g),
      (__attribute__((address_space(3))) void*)(l), 16, 0, 0);
}

__device__ __forceinline__ uint32_t pk2(float lo, float hi) {
  union { bf16_t b[2]; uint32_t u; } p;
  p.b[0] = (bf16_t)lo; p.b[1] = (bf16_t)hi;
  return p.u;  // compiler fuses to v_cvt_pk_bf16_f32
}

// ---------------- fused prep: cvt x -> bf16; transpose+cvt w_qkv, w_proj ----
// blocks [0,4096): xb; [4096,7168): wqkvT; [7168,8192): wprojT
__global__ __launch_bounds__(256) void k_prep(
    const float* __restrict__ x, const float* __restrict__ w_qkv,
    const float* __restrict__ w_proj, bf16_t* __restrict__ xb,
    bf16_t* __restrict__ wqkvT, bf16_t* __restrict__ wprojT) {
  __shared__ float tile[32][33];
  const int b = blockIdx.x;
  if (b < 4096) {
    int i = b * 256 + threadIdx.x;
    float4 v = ((const float4*)x)[i];
    union { bf16_t bb[4]; uint64_t u; } p;
    p.bb[0] = (bf16_t)v.x; p.bb[1] = (bf16_t)v.y;
    p.bb[2] = (bf16_t)v.z; p.bb[3] = (bf16_t)v.w;
    ((uint64_t*)xb)[i] = p.u;
    return;
  }
  const float* in; bf16_t* out; int R, C, c0, r0;
  if (b < 7168) {
    int bb = b - 4096; in = w_qkv; out = wqkvT; R = 1024; C = 3072;
    c0 = (bb % 96) * 32; r0 = (bb / 96) * 32;
  } else {
    int bb = b - 7168; in = w_proj; out = wprojT; R = 1024; C = 1024;
    c0 = (bb % 32) * 32; r0 = (bb / 32) * 32;
  }
  int tx = threadIdx.x & 31, ty = threadIdx.x >> 5;
#pragma unroll
  for (int i = 0; i < 4; i++) {
    int r = ty + i * 8;
    tile[r][tx] = in[(size_t)(r0 + r) * C + c0 + tx];
  }
  __syncthreads();
#pragma unroll
  for (int i = 0; i < 4; i++) {
    int c = ty + i * 8;
    out[(size_t)(c0 + c) * R + r0 + tx] = (bf16_t)tile[tx][c];
  }
}

// ---------------- QKV GEMM + bias + RoPE + scatter ----------------
__global__ __launch_bounds__(256) void k_qkv(
    const bf16_t* __restrict__ A,   // [4096][1024]
    const bf16_t* __restrict__ Bt,  // [3072][1024]
    const float* __restrict__ bias, // [3072]
    const float* __restrict__ cs,   // [4096][32]
    const float* __restrict__ sn,   // [4096][32]
    bf16_t* __restrict__ qb, bf16_t* __restrict__ kb, bf16_t* __restrict__ vT) {
  constexpr int K = 1024, BK = 32;
  __shared__ bf16_t As[128 * BK] __attribute__((aligned(16)));
  __shared__ bf16_t Bs[128 * BK] __attribute__((aligned(16)));
  const int t = threadIdx.x;
  const int lane = t & 63, w = t >> 6;
  const int lrow = lane & 15, quad = lane >> 4;
  const int m0 = blockIdx.y * 128, n0 = blockIdx.x * 128;
  const int wm = (w >> 1) * 64, wn = (w & 1) * 64;

  const floatx4 ZV = {0.f, 0.f, 0.f, 0.f};
  floatx4 acc[4][4];
#pragma unroll
  for (int i = 0; i < 4; i++)
#pragma unroll
    for (int j = 0; j < 4; j++) acc[i][j] = ZV;

  for (int kt = 0; kt < K; kt += BK) {
#pragma unroll
    for (int r = 0; r < 2; r++) {
      int idx = r * 256 + t;
      int lbase = (r * 256 + w * 64) * 8;
      async_ld16(&A[(size_t)(m0 + (idx >> 2)) * K + kt + (idx & 3) * 8], &As[lbase]);
      async_ld16(&Bt[(size_t)(n0 + (idx >> 2)) * K + kt + (idx & 3) * 8], &Bs[lbase]);
    }
    __syncthreads();
    bf16x8 af[4], bf[4];
#pragma unroll
    for (int i = 0; i < 4; i++)
      af[i] = *(const bf16x8*)&As[(wm + i * 16 + lrow) * BK + quad * 8];
#pragma unroll
    for (int i = 0; i < 4; i++)
      bf[i] = *(const bf16x8*)&Bs[(wn + i * 16 + lrow) * BK + quad * 8];
#pragma unroll
    for (int mi = 0; mi < 4; mi++)
#pragma unroll
      for (int ni = 0; ni < 4; ni++)
        acc[mi][ni] = __builtin_amdgcn_mfma_f32_16x16x32_bf16(af[mi], bf[ni], acc[mi][ni], 0, 0, 0);
    __syncthreads();
  }

  // Epilogue: wave covers cols [c0, c0+64) = exactly one head of one of q/k/v.
  const int c0 = n0 + wn;
  const int seg = c0 >> 10;           // 0=q 1=k 2=v
  const int h = (c0 & 1023) >> 6;
  float bv[4];
#pragma unroll
  for (int ni = 0; ni < 4; ni++) bv[ni] = bias[c0 + ni * 16 + lrow];

  if (seg < 2) {
    bf16_t* base = ((seg == 0) ? qb : kb) + (size_t)h * TOK * HDIM;
    const float qs = (seg == 0) ? SCALE_LOG2E : 1.0f;
#pragma unroll
    for (int mi = 0; mi < 4; mi++) {
#pragma unroll
      for (int reg = 0; reg < 4; reg++) {
        const int r = m0 + wm + mi * 16 + quad * 4 + reg;
        const float c_lo = cs[r * 32 + lrow];
        const float c_hi = cs[r * 32 + 16 + lrow];
        const float s_lo = sn[r * 32 + lrow];
        const float s_hi = sn[r * 32 + 16 + lrow];
        const float v0 = acc[mi][0][reg] + bv[0];
        const float v1 = acc[mi][1][reg] + bv[1];
        const float v2 = acc[mi][2][reg] + bv[2];
        const float v3 = acc[mi][3][reg] + bv[3];
        // RoPE: d<32: v*cos - v[d+32]*sin ; d>=32: v*cos + v[d-32]*sin
        const float o0 = (v0 * c_lo - v2 * s_lo) * qs;
        const float o1 = (v1 * c_hi - v3 * s_hi) * qs;
        const float o2 = (v2 * c_lo + v0 * s_lo) * qs;
        const float o3 = (v3 * c_hi + v1 * s_hi) * qs;
        bf16_t* rp = base + (size_t)r * HDIM + lrow;
        rp[0]  = (bf16_t)o0;
        rp[16] = (bf16_t)o1;
        rp[32] = (bf16_t)o2;
        rp[48] = (bf16_t)o3;
      }
    }
  } else {
    // V: store transposed [h][d][n]; 4 acc regs = 4 consecutive rows -> 8B store
    bf16_t* base = vT + (size_t)h * HDIM * TOK;
#pragma unroll
    for (int mi = 0; mi < 4; mi++) {
      const int rbase = m0 + wm + mi * 16 + quad * 4;
#pragma unroll
      for (int ni = 0; ni < 4; ni++) {
        union { bf16_t b[4]; uint64_t u; } p;
#pragma unroll
        for (int reg = 0; reg < 4; reg++) p.b[reg] = (bf16_t)(acc[mi][ni][reg] + bv[ni]);
        *(uint64_t*)&base[(size_t)(ni * 16 + lrow) * TOK + rbase] = p.u;
      }
    }
  }
}

// ---------------- flash attention v10: v9 + 1-iter PV software pipeline ----
// v9 measurement: permlane P-exchange is correct but sits serially between
// exp2 and PV -> VALUBusy 36->47, dur 99->106. Bank conflicts identical
// 1.376M in v7/v9 => they never came from Ps; LDS pipe has headroom. The
// kernel is dependency-latency-bound at 2 waves/SIMD.
// v10: PV for tile i-1 issues at the TOP of iter i purely from registers
// (pf, vf carried), overlapping kf loads + QK of tile i. The whole
// exp2+pack+permlane chain of tile i now has its consumer one iteration
// away -> off the critical path. V is triple-buffered (PV reads slot i-1
// while prefetch writes slot i+1; distinct mod 3). vf(i) is pre-read into
// regs during iter i (barrier's lgkmcnt(0) publishes them for iter i+1).
__global__ __launch_bounds__(256, 2) void k_attn(
    const bf16_t* __restrict__ qb, const bf16_t* __restrict__ kb,
    const bf16_t* __restrict__ vT, bf16_t* __restrict__ ao) {
  __shared__ bf16_t Ks[2][64 * 64] __attribute__((aligned(16)));
  __shared__ bf16_t Vs[3][64 * 64] __attribute__((aligned(16)));
  __shared__ float Lmrg[128];
  const int t = threadIdx.x, lane = t & 63, w = t >> 6;
  const int lrow = lane & 15, quad = lane >> 4;
  const int qg = w & 1, kh = w >> 1;
  const int h = blockIdx.x & 15;
  const int q0 = (blockIdx.x >> 4) * 128;
  const bf16_t* qh = qb + (size_t)h * TOK * HDIM;
  const bf16_t* khp = kb + (size_t)h * TOK * HDIM;
  const bf16_t* vhp = vT + (size_t)h * HDIM * TOK;

  // Staging (256 threads, 2 rounds each for K and V; 64 rows x 8 chunks).
  // XOR swizzle folded into the GLOBAL side; LDS side lane-linear.
  const int ksrc = (t >> 3) * HDIM + (((t & 7) ^ ((t >> 3) & 7)) * 8);
  const int vsrc = (t >> 3) * TOK + (((t & 7) ^ ((t >> 3) & 7)) * 8);

  // Q B-fragments (B[n=q][k=d]) straight from global, once.
  bf16x8 qf[4][2];
#pragma unroll
  for (int ni = 0; ni < 4; ni++)
#pragma unroll
    for (int ks = 0; ks < 2; ks++)
      qf[ni][ks] = *(const bf16x8*)&qh[(size_t)(q0 + qg * 64 + ni * 16 + lrow) * HDIM + ks * 32 + quad * 8];

  const floatx4 ZV = {0.f, 0.f, 0.f, 0.f};
  floatx4 o[4][4];            // O^T [d-tile][ni] over this wave's key-half
  floatx4 lacc[4] = {ZV, ZV, ZV, ZV};
#pragma unroll
  for (int d = 0; d < 4; d++)
#pragma unroll
    for (int ni = 0; ni < 4; ni++) o[d][ni] = ZV;

  // Prologue: stage tile 0 into K buffer 0 / V slot 0.
#pragma unroll
  for (int r = 0; r < 2; r++) {
    async_ld16(&khp[(size_t)(r * 32) * HDIM + ksrc], &Ks[0][r * 2048 + t * 8]);
    async_ld16(&vhp[(size_t)(r * 32) * TOK + vsrc], &Vs[0][r * 2048 + t * 8]);
  }

  bf16x8 pf[4];  // P fragment of tile it (consumed at it+1)
  bf16x8 vf[4];  // V fragment of tile it (consumed at it+1)

  for (int it = 0; it < TOK / 64; ++it) {
    const int b = it & 1;
    __syncthreads();   // Ks[b] / Vs[it%3] staged (prefetched a full phase ago)
    if (it + 1 < TOK / 64) {
      const int j1 = (it + 1) * 64;
      const int vs1 = (it + 1) % 3;
#pragma unroll
      for (int r = 0; r < 2; r++) {
        async_ld16(&khp[((size_t)j1 + r * 32) * HDIM + ksrc], &Ks[b ^ 1][r * 2048 + t * 8]);
        async_ld16(&vhp[(size_t)(r * 32) * TOK + j1 + vsrc], &Vs[vs1][r * 2048 + t * 8]);
      }
    }

    // ---- PV for tile it-1: pure register MFMAs, issue immediately.
    if (it > 0) {
#pragma unroll
      for (int dt = 0; dt < 4; dt++)
#pragma unroll
        for (int ni = 0; ni < 4; ni++)
          o[dt][ni] = __builtin_amdgcn_mfma_f32_16x16x32_bf16(vf[dt], pf[ni], o[dt][ni], 0, 0, 0);
    }

    // ---- S^T quadrant: keys kh*32+mi*16+quad*4+reg, q = qg*64+ni*16+lrow
    floatx4 s[2][4];
#pragma unroll
    for (int mi = 0; mi < 2; mi++)
#pragma unroll
      for (int ni = 0; ni < 4; ni++) s[mi][ni] = ZV;
#pragma unroll
    for (int ks = 0; ks < 2; ks++)
#pragma unroll
      for (int mi = 0; mi < 2; mi++) {
        bf16x8 kf = *(const bf16x8*)&Ks[b][(kh * 32 + mi * 16 + lrow) * 64 + (((ks * 4 + quad) ^ (lrow & 7)) * 8)];
#pragma unroll
        for (int ni = 0; ni < 4; ni++)
          s[mi][ni] = __builtin_amdgcn_mfma_f32_16x16x32_bf16(kf, qf[ni][ks], s[mi][ni], 0, 0, 0);
      }

    // ---- V fragments of tile it -> regs (used next iter; LDS latency
    // retired by the lgkmcnt(0) at the next barrier).
#pragma unroll
    for (int dt = 0; dt < 4; dt++)
      vf[dt] = *(const bf16x8*)&Vs[it % 3][(dt * 16 + lrow) * 64 + (((kh * 4 + quad) ^ (lrow & 7)) * 8)];

    // ---- P = exp2(S) (fixed-max), vector l-partials
#pragma unroll
    for (int mi = 0; mi < 2; mi++)
#pragma unroll
      for (int ni = 0; ni < 4; ni++) {
#pragma unroll
        for (int reg = 0; reg < 4; reg++)
          s[mi][ni][reg] = __builtin_amdgcn_exp2f(s[mi][ni][reg]);
        lacc[ni] += s[mi][ni];
      }

    // ---- S^T frag -> PV B-frag, fully in-register (proven v9 mapping):
    // stage1 permlane32_swap: lane-bit5 <-> pack bit (A/B)
    // stage2 permlane16_swap: lane-bit4 <-> stage1 reg index
#pragma unroll
    for (int ni = 0; ni < 4; ni++) {
      uint32_t A0 = pk2(s[0][ni][0], s[0][ni][1]);
      uint32_t A1 = pk2(s[0][ni][2], s[0][ni][3]);
      uint32_t B0 = pk2(s[1][ni][0], s[1][ni][1]);
      uint32_t B1 = pk2(s[1][ni][2], s[1][ni][3]);
      auto u0 = __builtin_amdgcn_permlane32_swap(A0, B0, false, false);  // {U00,U10}
      auto u1 = __builtin_amdgcn_permlane32_swap(A1, B1, false, false);  // {U01,U11}
      auto c0 = __builtin_amdgcn_permlane16_swap(u0[0], u0[1], false, false);  // {R00,R10}
      auto c1 = __builtin_amdgcn_permlane16_swap(u1[0], u1[1], false, false);  // {R01,R11}
      union { uint32_t d[4]; bf16x8 v; } pp;
      pp.d[0] = c0[0]; pp.d[1] = c1[0]; pp.d[2] = c0[1]; pp.d[3] = c1[1];
      pf[ni] = pp.v;
    }
  }

  // ---- drain: PV for the last tile (pure regs).
#pragma unroll
  for (int dt = 0; dt < 4; dt++)
#pragma unroll
    for (int ni = 0; ni < 4; ni++)
      o[dt][ni] = __builtin_amdgcn_mfma_f32_16x16x32_bf16(vf[dt], pf[ni], o[dt][ni], 0, 0, 0);

  // ---- epilogue: merge kh halves. qg=0 -> Ks region (16KB), qg=1 -> Vs.
  __syncthreads();
  float* Mrg = (qg == 0) ? (float*)&Ks[0][0] : (float*)&Vs[0][0];  // 64q x 64d fp32
  float lq[4];
#pragma unroll
  for (int ni = 0; ni < 4; ni++) {
    float l = lacc[ni][0] + lacc[ni][1] + lacc[ni][2] + lacc[ni][3];
    l += __shfl_xor(l, 16, 64);
    l += __shfl_xor(l, 32, 64);
    lq[ni] = l;
  }
  if (kh == 1) {
#pragma unroll
    for (int ni = 0; ni < 4; ni++) {
#pragma unroll
      for (int dt = 0; dt < 4; dt++)
        *(floatx4*)&Mrg[(ni * 16 + lrow) * 64 + dt * 16 + quad * 4] = o[dt][ni];
      if (quad == 0) Lmrg[qg * 64 + ni * 16 + lrow] = lq[ni];
    }
  }
  __syncthreads();
  if (kh == 0) {
#pragma unroll
    for (int ni = 0; ni < 4; ni++) {
      const float l = lq[ni] + Lmrg[qg * 64 + ni * 16 + lrow];
      const float inv = 1.0f / l;
      const int qrow = q0 + qg * 64 + ni * 16 + lrow;
#pragma unroll
      for (int dt = 0; dt < 4; dt++) {
        floatx4 ov = *(const floatx4*)&Mrg[(ni * 16 + lrow) * 64 + dt * 16 + quad * 4];
        union { bf16_t b4[4]; uint64_t u; } p;
#pragma unroll
        for (int reg = 0; reg < 4; reg++) p.b4[reg] = (bf16_t)((o[dt][ni][reg] + ov[reg]) * inv);
        *(uint64_t*)&ao[(size_t)qrow * DIM_ + h * HDIM + dt * 16 + quad * 4] = p.u;
      }
    }
  }
}

// ---------------- proj GEMM + bias (fp32 out), 64x128 tiles ----------------
__global__ __launch_bounds__(256) void k_proj(
    const bf16_t* __restrict__ A,   // [4096][1024]
    const bf16_t* __restrict__ Bt,  // [1024][1024]
    const float* __restrict__ bias, float* __restrict__ out) {
  constexpr int K = 1024, BK = 32;
  __shared__ bf16_t As[64 * BK] __attribute__((aligned(16)));
  __shared__ bf16_t Bs[128 * BK] __attribute__((aligned(16)));
  const int t = threadIdx.x;
  const int lane = t & 63, w = t >> 6;
  const int lrow = lane & 15, quad = lane >> 4;
  const int m0 = blockIdx.y * 64, n0 = blockIdx.x * 128;
  const int wm = (w >> 1) * 32, wn = (w & 1) * 64;

  const floatx4 ZV = {0.f, 0.f, 0.f, 0.f};
  floatx4 acc[2][4];
#pragma unroll
  for (int i = 0; i < 2; i++)
#pragma unroll
    for (int j = 0; j < 4; j++) acc[i][j] = ZV;

  for (int kt = 0; kt < K; kt += BK) {
    async_ld16(&A[(size_t)(m0 + (t >> 2)) * K + kt + (t & 3) * 8], &As[w * 512]);
#pragma unroll
    for (int r = 0; r < 2; r++) {
      int idx = r * 256 + t;
      async_ld16(&Bt[(size_t)(n0 + (idx >> 2)) * K + kt + (idx & 3) * 8],
                 &Bs[(r * 256 + w * 64) * 8]);
    }
    __syncthreads();
    bf16x8 af[2], bf[4];
#pragma unroll
    for (int i = 0; i < 2; i++)
      af[i] = *(const bf16x8*)&As[(wm + i * 16 + lrow) * BK + quad * 8];
#pragma unroll
    for (int i = 0; i < 4; i++)
      bf[i] = *(const bf16x8*)&Bs[(wn + i * 16 + lrow) * BK + quad * 8];
#pragma unroll
    for (int mi = 0; mi < 2; mi++)
#pragma unroll
      for (int ni = 0; ni < 4; ni++)
        acc[mi][ni] = __builtin_amdgcn_mfma_f32_16x16x32_bf16(af[mi], bf[ni], acc[mi][ni], 0, 0, 0);
    __syncthreads();
  }

  const int c0 = n0 + wn;
#pragma unroll
  for (int ni = 0; ni < 4; ni++) {
    float bv = bias[c0 + ni * 16 + lrow];
#pragma unroll
    for (int mi = 0; mi < 2; mi++)
#pragma unroll
      for (int reg = 0; reg < 4; reg++) {
        int r = m0 + wm + mi * 16 + quad * 4 + reg;
        out[(size_t)r * DIM_ + c0 + ni * 16 + lrow] = acc[mi][ni][reg] + bv;
      }
  }
}

extern "C" void kernel_launch(void* const* d_in, const int* in_sizes, int n_in,
                              void* d_out, int out_size, void* d_ws, size_t ws_size,
                              hipStream_t stream) {
  const float* x      = (const float*)d_in[0];
  const float* cs     = (const float*)d_in[1];
  const float* sn     = (const float*)d_in[2];
  const float* w_qkv  = (const float*)d_in[3];
  const float* b_qkv  = (const float*)d_in[4];
  const float* w_proj = (const float*)d_in[5];
  const float* b_proj = (const float*)d_in[6];
  float* out = (float*)d_out;

  char* ws = (char*)d_ws;
  bf16_t* xb     = (bf16_t*)(ws);
  bf16_t* wqkvT  = (bf16_t*)(ws + 8388608);
  bf16_t* wprojT = (bf16_t*)(ws + 14680064);
  bf16_t* qb     = (bf16_t*)(ws + 16777216);
  bf16_t* kb     = (bf16_t*)(ws + 25165824);
  bf16_t* vT     = (bf16_t*)(ws + 33554432);
  bf16_t* ao     = xb;  // x is dead after k_qkv; reuse its region

  k_prep<<<dim3(8192), dim3(256), 0, stream>>>(x, w_qkv, w_proj, xb, wqkvT, wprojT);
  k_qkv<<<dim3(24, 32), dim3(256), 0, stream>>>(xb, wqkvT, b_qkv, cs, sn, qb, kb, vT);
  k_attn<<<dim3(512), dim3(256), 0, stream>>>(qb, kb, vT, ao);
  k_proj<<<dim3(8, 64), dim3(256), 0, stream>>>(ao, wprojT, b_proj, out);
}